// Round 1
// baseline (228.657 us; speedup 1.0000x reference)
//
#include <hip/hip_runtime.h>
#include <math.h>

typedef _Float16 f16;
typedef _Float16 f16x2 __attribute__((ext_vector_type(2)));
typedef _Float16 f16x8 __attribute__((ext_vector_type(8)));
typedef float    f32x4 __attribute__((ext_vector_type(4)));
typedef float    f32x16 __attribute__((ext_vector_type(16)));

#define NB 4096
#define LT 512
#define NC 16
#define NS 32

// workspace layout (bytes)
#define WS_P0     0                     // 32 f32, softmax(init)*256
#define WS_SIG    128                   // 32 f32, sigmoid(acc)*256
#define WS_SUMSIG 256                   // 1 f32
#define WS_FWDT   512                   // 16384 f16 = 32768 B
#define WS_BWDT   (512 + 32768)
#define WS_F      (512 + 65536)         // 32*4096 f32
#define WS_G      (WS_F + 32*4096*4)

#if __has_builtin(__builtin_amdgcn_exp2f)
#define EXP2F __builtin_amdgcn_exp2f
#else
#define EXP2F exp2f
#endif

// ---------------- prep: softmaxes + fragment-ordered fp16 transition tables ----
__global__ __launch_bounds__(512) void pdfa_prep(const float* __restrict__ tlogit,
                                                 const float* __restrict__ ilogit,
                                                 const float* __restrict__ alogit,
                                                 char* __restrict__ ws) {
    int tid = threadIdx.x;           // 512 threads = one (p,c) row each
    f16* fwdT = (f16*)(ws + WS_FWDT);
    f16* bwdT = (f16*)(ws + WS_BWDT);
    int p = tid >> 4, c = tid & 15;
    const float* row = tlogit + p * 512 + c * 32;
    float mx = row[0];
    for (int n = 1; n < 32; ++n) mx = fmaxf(mx, row[n]);
    float s = 0.f;
    for (int n = 0; n < 32; ++n) s += expf(row[n] - mx);
    float inv = 1.f / s;
    int g = p >> 3, ht = (p >> 2) & 1, d = p & 3;
    int chalf = c >> 3, j = c & 7;
    for (int n = 0; n < 32; ++n) {
        float tv = expf(row[n] - mx) * inv;
        // fwd table: GEMM D[m=n']=sum_k T[p,c,n']*y[k], A row m = lane&31 = n
        {
            int ks = 8 * g + 2 * d + chalf;
            int l = 32 * ht + n;
            fwdT[ks * 512 + l * 8 + j] = (f16)tv;
        }
        // bwd table: D[m=p]=sum_{(c,n)} T[p,c,n]*x[c]g[n], A row m = p
        {
            int g2 = n >> 3, h2 = (n >> 2) & 1, d2 = n & 3;
            int ks = 8 * g2 + 2 * d2 + chalf;
            int l = 32 * h2 + p;
            bwdT[ks * 512 + l * 8 + j] = (f16)tv;
        }
    }
    if (tid < 32) {
        float m0 = ilogit[0];
        for (int n = 1; n < 32; ++n) m0 = fmaxf(m0, ilogit[n]);
        float s0 = 0.f;
        for (int n = 0; n < 32; ++n) s0 += expf(ilogit[n] - m0);
        ((float*)(ws + WS_P0))[tid]  = 256.f * expf(ilogit[tid] - m0) / s0;
        ((float*)(ws + WS_SIG))[tid] = 256.f / (1.f + expf(-alogit[tid]));
    }
    if (tid == 0) {
        float ss = 0.f;
        for (int n = 0; n < 32; ++n) ss += 1.f / (1.f + expf(-alogit[n]));
        *(float*)(ws + WS_SUMSIG) = ss;
    }
}

// ---------------- main: 256 independent wave-chains (128 seq-tiles x fwd/bwd) --
#define EC(v) ((f16)EXP2F((v) * 1.44269504089f))

#define XLOAD(B0,B1,B2,B3,T) { const f32x4* sp_ = (const f32x4*)(xbase + (size_t)(T) * NC); \
    B0 = sp_[0]; B1 = sp_[1]; B2 = sp_[2]; B3 = sp_[3]; }

#define XCONV(B0,B1,B2,B3) { \
    xq[0] = f16x2{EC(B0[0]), EC(B0[1])}; \
    xq[1] = f16x2{EC(B0[2]), EC(B0[3])}; \
    xq[2] = f16x2{EC(B1[0]), EC(B1[1])}; \
    xq[3] = f16x2{EC(B1[2]), EC(B1[3])}; \
    xq[4] = f16x2{EC(B2[0]), EC(B2[1])}; \
    xq[5] = f16x2{EC(B2[2]), EC(B2[3])}; \
    xq[6] = f16x2{EC(B3[0]), EC(B3[1])}; \
    xq[7] = f16x2{EC(B3[2]), EC(B3[3])}; }

// one K-step: broadcast own-half state scalar, 4x v_pk_mul_f16, one MFMA
#define KSTEP(KS, ACC, CIN) { \
    enum { ks_ = (KS), ir_ = 2*((KS)>>3) + (((KS)>>2)&1), ch_ = ((KS)&1)*4, sel_ = ((KS)>>1)&1 }; \
    f16 pv_ = ppk[ir_][sel_]; \
    f16x2 pb_ = {pv_, pv_}; \
    f16x2 y0_ = pb_ * xq[ch_+0], y1_ = pb_ * xq[ch_+1], y2_ = pb_ * xq[ch_+2], y3_ = pb_ * xq[ch_+3]; \
    f16x8 bf_ = {y0_[0],y0_[1],y1_[0],y1_[1],y2_[0],y2_[1],y3_[0],y3_[1]}; \
    ACC = __builtin_amdgcn_mfma_f32_32x32x16_f16(af[ks_], bf_, CIN, 0, 0, 0); }

#define STEPBODY() { \
    f32x16 a0, a1; \
    KSTEP(0,  a0, z) KSTEP(16, a1, z) \
    KSTEP(1,  a0, a0) KSTEP(17, a1, a1) \
    KSTEP(2,  a0, a0) KSTEP(18, a1, a1) \
    KSTEP(3,  a0, a0) KSTEP(19, a1, a1) \
    KSTEP(4,  a0, a0) KSTEP(20, a1, a1) \
    KSTEP(5,  a0, a0) KSTEP(21, a1, a1) \
    KSTEP(6,  a0, a0) KSTEP(22, a1, a1) \
    KSTEP(7,  a0, a0) KSTEP(23, a1, a1) \
    KSTEP(8,  a0, a0) KSTEP(24, a1, a1) \
    KSTEP(9,  a0, a0) KSTEP(25, a1, a1) \
    KSTEP(10, a0, a0) KSTEP(26, a1, a1) \
    KSTEP(11, a0, a0) KSTEP(27, a1, a1) \
    KSTEP(12, a0, a0) KSTEP(28, a1, a1) \
    KSTEP(13, a0, a0) KSTEP(29, a1, a1) \
    KSTEP(14, a0, a0) KSTEP(30, a1, a1) \
    KSTEP(15, a0, a0) KSTEP(31, a1, a1) \
    pfin[0]=a0[0]+a1[0];   pfin[1]=a0[1]+a1[1];   pfin[2]=a0[2]+a1[2];   pfin[3]=a0[3]+a1[3]; \
    pfin[4]=a0[4]+a1[4];   pfin[5]=a0[5]+a1[5];   pfin[6]=a0[6]+a1[6];   pfin[7]=a0[7]+a1[7]; \
    pfin[8]=a0[8]+a1[8];   pfin[9]=a0[9]+a1[9];   pfin[10]=a0[10]+a1[10]; pfin[11]=a0[11]+a1[11]; \
    pfin[12]=a0[12]+a1[12]; pfin[13]=a0[13]+a1[13]; pfin[14]=a0[14]+a1[14]; pfin[15]=a0[15]+a1[15]; \
    ppk[0] = f16x2{(f16)pfin[0],  (f16)pfin[1]}; \
    ppk[1] = f16x2{(f16)pfin[2],  (f16)pfin[3]}; \
    ppk[2] = f16x2{(f16)pfin[4],  (f16)pfin[5]}; \
    ppk[3] = f16x2{(f16)pfin[6],  (f16)pfin[7]}; \
    ppk[4] = f16x2{(f16)pfin[8],  (f16)pfin[9]}; \
    ppk[5] = f16x2{(f16)pfin[10], (f16)pfin[11]}; \
    ppk[6] = f16x2{(f16)pfin[12], (f16)pfin[13]}; \
    ppk[7] = f16x2{(f16)pfin[14], (f16)pfin[15]}; }

__global__ __launch_bounds__(64, 1) void pdfa_main(const float* __restrict__ login,
                                                   char* __restrict__ ws) {
    const int lane = threadIdx.x;
    const int br = lane & 31, hi = lane >> 5;
    const int bid = blockIdx.x;
    const int dir = bid & 1;               // 0 = forward (t 0..255), 1 = backward (t 511..256)
    const int b0 = (bid >> 1) << 5;

    // constant A-operand fragments (transition table), 32 frags x 16B = 128 VGPRs
    const char* tblb = ws + (dir ? WS_BWDT : WS_FWDT);
    f16x8 af[32];
#pragma unroll
    for (int ks = 0; ks < 32; ++ks)
        af[ks] = *(const f16x8*)(tblb + ks * 1024 + lane * 16);

    // init state vector (own half-wave's 16 states as 8 packed regs)
    const float* initv = (const float*)(ws + (dir ? WS_SIG : WS_P0));
    f16x2 ppk[8];
#pragma unroll
    for (int i = 0; i < 8; ++i) {
        int s0 = 8 * (i >> 1) + 4 * hi + 2 * (i & 1);
        ppk[i] = f16x2{(f16)initv[s0], (f16)initv[s0 + 1]};
    }

    const float* xbase = login + (size_t)(b0 + br) * (LT * NC);
    const f32x16 z{};
    f32x16 pfin{};
    f16x2 xq[8];
    f32x4 xa0, xa1, xa2, xa3, xb0, xb1, xb2, xb3;

#define TT(S) (dir ? (511 - (S)) : (S))
    XLOAD(xa0, xa1, xa2, xa3, TT(0))
    XLOAD(xb0, xb1, xb2, xb3, TT(1))

    for (int s = 0; s < 256; s += 2) {
        XCONV(xa0, xa1, xa2, xa3)
        XLOAD(xa0, xa1, xa2, xa3, TT(s + 2))   // depth-2 prefetch (t<=257 / >=254: in range)
        STEPBODY()
        XCONV(xb0, xb1, xb2, xb3)
        XLOAD(xb0, xb1, xb2, xb3, TT(s + 3))
        STEPBODY()
    }
#undef TT

    // write fp32 result vector: f (fwd) or g (bwd), laid out [state][b]
    float* outv = (float*)(ws + (dir ? WS_G : WS_F));
#pragma unroll
    for (int r = 0; r < 16; ++r) {
        int st = (r & 3) + 8 * (r >> 2) + 4 * hi;
        outv[st * NB + b0 + br] = pfin[r];
    }
}

// ---------------- combine: out[b] = log( f.g / 65536 + 1e-20*sum(sigma) ) ------
__global__ __launch_bounds__(256) void pdfa_combine(const char* __restrict__ ws,
                                                    float* __restrict__ out) {
    int b = blockIdx.x * 256 + threadIdx.x;
    const float* f = (const float*)(ws + WS_F);
    const float* g = (const float*)(ws + WS_G);
    float ss = *(const float*)(ws + WS_SUMSIG);
    float dot = 0.f;
#pragma unroll
    for (int s2 = 0; s2 < 32; ++s2)
        dot = fmaf(f[s2 * NB + b], g[s2 * NB + b], dot);
    out[b] = logf(dot * (1.f / 65536.f) + 1e-20f * ss);
}

extern "C" void kernel_launch(void* const* d_in, const int* in_sizes, int n_in,
                              void* d_out, int out_size, void* d_ws, size_t ws_size,
                              hipStream_t stream) {
    const float* login = (const float*)d_in[0];
    const float* ilog  = (const float*)d_in[1];
    const float* tlog  = (const float*)d_in[2];
    const float* alog  = (const float*)d_in[3];
    char* ws = (char*)d_ws;

    pdfa_prep<<<1, 512, 0, stream>>>(tlog, ilog, alog, ws);
    pdfa_main<<<256, 64, 0, stream>>>(login, ws);
    pdfa_combine<<<NB / 256, 256, 0, stream>>>(ws, (float*)d_out);
}